// Round 8
// baseline (267.182 us; speedup 1.0000x reference)
//
#include <hip/hip_runtime.h>
#include <cstdint>

#define BB 32768
#define II 1024
#define HH 1024
#define SPLIT 8
#define KCH (BB/SPLIT)      // 4096
#define NT1 (II/64)         // 16 K-tiles (gemm1)
#define NT2 (KCH/64)        // 64 K-tiles per split (gemm2)

typedef _Float16 f16;
typedef _Float16 f16x4 __attribute__((ext_vector_type(4)));
typedef _Float16 f16x8 __attribute__((ext_vector_type(8)));
typedef float f32x4 __attribute__((ext_vector_type(4)));

typedef const __attribute__((address_space(1))) void gvoid_t;
typedef __attribute__((address_space(3))) void lvoid_t;

__device__ __forceinline__ void gload16(const void* g, void* l){
    __builtin_amdgcn_global_load_lds((gvoid_t*)g, (lvoid_t*)l, 16, 0, 0);
}

__device__ __forceinline__ float tanh_fast(float s){
    float a = fabsf(s);
    float e = __expf(-2.0f * a);
    float t = __fdividef(1.0f - e, 1.0f + e);
    return s < 0.0f ? -t : t;
}

// in [R][C] f32 -> cvt_out [R][C] f16 (optional) + tr_out [C][R] f16. 64x64 tiles.
__global__ __launch_bounds__(256) void k_prep(const float* __restrict__ in,
                                              f16* __restrict__ cvt_out,
                                              f16* __restrict__ tr_out,
                                              int C, int R){
    __shared__ float lt[64*67];
    const int t = threadIdx.x;
    const int r0 = blockIdx.x*64, c0 = blockIdx.y*64;
    #pragma unroll
    for (int p=0; p<4; ++p){
        int r = p*16 + (t>>4);
        int c = (t&15)*4;
        float4 v = *(const float4*)&in[(size_t)(r0+r)*C + c0 + c];
        if (cvt_out){
            f16x4 hv = {(f16)v.x,(f16)v.y,(f16)v.z,(f16)v.w};
            *(f16x4*)&cvt_out[(size_t)(r0+r)*C + c0 + c] = hv;
        }
        lt[r*67 + c+0] = v.x;
        lt[r*67 + c+1] = v.y;
        lt[r*67 + c+2] = v.z;
        lt[r*67 + c+3] = v.w;
    }
    __syncthreads();
    const int c = t>>2, rb = (t&3)*16;
    f16x8 a, b;
    #pragma unroll
    for (int e=0; e<8; ++e) a[e] = (f16)lt[(rb+e)*67 + c];
    #pragma unroll
    for (int e=0; e<8; ++e) b[e] = (f16)lt[(rb+8+e)*67 + c];
    f16* o = &tr_out[(size_t)(c0+c)*R + r0 + rb];
    *(f16x8*)o = a;
    *(f16x8*)(o+8) = b;
}

// stage one 128x64-f16 tile (16KB) into linear LDS, source inverse-swizzled.
// LDS image byte b: row = b>>7, col c = (b&127) ^ (((b>>7)&7)<<4).
// MT=false: panel flat [row][ld] k-major. MT=true: panel 16x16 micro-tiled
// [h>>4][b>>4][h&15][b&15] f16.
template<bool MT>
__device__ __forceinline__ void stage_half(const f16* __restrict__ panel, int ld,
                                           int row0, int kcol0, char* lds_half,
                                           int wid, int lane){
    #pragma unroll
    for (int r=0;r<2;++r){
        int o = r*8192 + wid*1024 + lane*16;
        int rr = o>>7;
        int c0 = (o&127) ^ ((rr&7)<<4);
        if constexpr (!MT){
            const f16* src = panel + (size_t)(row0 + rr)*ld + kcol0 + (c0>>1);
            gload16(src, lds_half + r*8192 + wid*1024);
        } else {
            int h    = row0 + rr;
            int babs = kcol0 + (c0>>1);
            const f16* src = panel + (((size_t)(h>>4)*(BB>>4) + (babs>>4))<<8)
                                   + ((h&15)<<4) + (babs&8);
            gload16(src, lds_half + r*8192 + wid*1024);
        }
    }
}

// 128x128 tile, BK=64, 8 waves (2m x 4n), 2-barrier dbuf K-loop, counted vmcnt.
// LDS 64KB -> 2 blocks/CU; acc[4][2] keeps regs <=128 for occupancy 4 waves/SIMD.
template<bool BMT>
__device__ __forceinline__ void kloop2(const f16* __restrict__ Ap, int lda, int arow0,
                                       const f16* __restrict__ Bp, int ldb, int brow0,
                                       int kbase, int nt, char* sm,
                                       f32x4 (&acc)[4][2])
{
    const int t = threadIdx.x, lane = t & 63, wid = t >> 6;
    const int wr = wid >> 2, wc = wid & 3;
    const int fr = lane & 15, kg = lane >> 4;
    char* const A0 = sm;
    char* const B0 = sm + 16384;
    char* const A1 = sm + 32768;
    char* const B1 = sm + 49152;
    const int rowA = wr*8192 + fr*128;          // wr*64 rows * 128B
    const int rowB = wc*4096 + fr*128;          // wc*32 rows * 128B
    const int ksw0 = ((kg    ) ^ (fr & 7)) << 4;
    const int ksw1 = ((kg + 4) ^ (fr & 7)) << 4;
    f16x8 af[4][2], bf[2][2];

    stage_half<false>(Ap, lda, arow0, kbase +  0, A0, wid, lane);
    stage_half<BMT  >(Bp, ldb, brow0, kbase +  0, B0, wid, lane);
    stage_half<false>(Ap, lda, arow0, kbase + 64, A1, wid, lane);
    stage_half<BMT  >(Bp, ldb, brow0, kbase + 64, B1, wid, lane);

    for (int tt = 0; tt < nt; ++tt){
        // buf(tt) ready when its 4 loads drained; 4 newer (tile tt+1) may fly
        if (tt < nt-1){ asm volatile("s_waitcnt vmcnt(4)" ::: "memory"); }
        else          { asm volatile("s_waitcnt vmcnt(0)" ::: "memory"); }
        __builtin_amdgcn_s_barrier();
        char* const A = (tt & 1) ? A1 : A0;
        char* const B = (tt & 1) ? B1 : B0;
        #pragma unroll
        for (int m_=0;m_<4;++m_){
            af[m_][0] = *(const f16x8*)(A + rowA + m_*2048 + ksw0);
            af[m_][1] = *(const f16x8*)(A + rowA + m_*2048 + ksw1);
        }
        #pragma unroll
        for (int n_=0;n_<2;++n_){
            bf[n_][0] = *(const f16x8*)(B + rowB + n_*2048 + ksw0);
            bf[n_][1] = *(const f16x8*)(B + rowB + n_*2048 + ksw1);
        }
        asm volatile("s_waitcnt lgkmcnt(0)" ::: "memory");
        __builtin_amdgcn_sched_barrier(0);
        __builtin_amdgcn_s_barrier();          // all waves done reading buf(tt)
        if (tt + 2 < nt){                      // restage buf(tt) with tile tt+2
            stage_half<false>(Ap, lda, arow0, kbase + (tt+2)*64, A, wid, lane);
            stage_half<BMT  >(Bp, ldb, brow0, kbase + (tt+2)*64, B, wid, lane);
        }
        __builtin_amdgcn_s_setprio(1);
        #pragma unroll
        for (int m_=0;m_<4;++m_)
            #pragma unroll
            for (int n_=0;n_<2;++n_)
                #pragma unroll
                for (int ks_=0;ks_<2;++ks_)
                    acc[m_][n_] = __builtin_amdgcn_mfma_f32_16x16x32_f16(
                        af[m_][ks_], bf[n_][ks_], acc[m_][n_], 0, 0, 0);
        __builtin_amdgcn_s_setprio(0);
    }
}

// GEMM1: D[b][h] = sum_i xf[b][i]*wt[h][i]; hidden[b][h]=tanh, ht=f16(tanh) micro-tiled.
__global__ __launch_bounds__(512,4) void k_gemm1(const f16* __restrict__ xf,
                                                 const f16* __restrict__ wt,
                                                 float* __restrict__ hidden,
                                                 f16* __restrict__ ht){
    __shared__ char sm[65536];
    // XCD-bijective swizzle: nwg=2048 -> 256/XCD; consecutive swz share btile (A-panel in L2)
    const int bid = (int)blockIdx.x;
    const int swz = (bid & 7)*256 + (bid >> 3);
    const int btile = swz >> 3, htile = swz & 7;
    f32x4 acc[4][2] = {};
    kloop2<false>(xf, II, btile*128, wt, II, htile*128, 0, NT1, sm, acc);

    const int t = threadIdx.x, lane = t & 63, wid = t >> 6;
    const int wr = wid >> 2, wc = wid & 3;
    const int fr = lane & 15, kg = lane >> 4;
    const int b_base = btile*128 + wr*64 + kg*4;
    const int h_base = htile*128 + wc*32 + fr;
    #pragma unroll
    for (int mf=0; mf<4; ++mf){
        const int b = b_base + mf*16;
        #pragma unroll
        for (int nf=0; nf<2; ++nf){
            const int h = h_base + nf*16;
            float t0 = tanh_fast(acc[mf][nf][0]);
            float t1 = tanh_fast(acc[mf][nf][1]);
            float t2 = tanh_fast(acc[mf][nf][2]);
            float t3 = tanh_fast(acc[mf][nf][3]);
            f16x4 hv = {(f16)t0,(f16)t1,(f16)t2,(f16)t3};
            *(f16x4*)&ht[(((size_t)(h>>4)*(BB>>4) + (b>>4))<<8) + ((h&15)<<4) + (b&15)] = hv;
            hidden[(size_t)(b+0)*HH + h] = t0;
            hidden[(size_t)(b+1)*HH + h] = t1;
            hidden[(size_t)(b+2)*HH + h] = t2;
            hidden[(size_t)(b+3)*HH + h] = t3;
        }
    }
}

// GEMM2: part[split] = xt-chunk @ ht-chunk^T, part micro-tiled [i>>4][h>>4][h&15][i&15].
__global__ __launch_bounds__(512,4) void k_gemm2(const f16* __restrict__ xt,
                                                 const f16* __restrict__ ht,
                                                 f16* __restrict__ part){
    __shared__ char sm[65536];
    // nwg=512 -> 64/XCD = 1 full split per XCD (panels stay in its L2)
    const int bid = (int)blockIdx.x;
    const int swz = (bid & 7)*64 + (bid >> 3);
    const int split = swz >> 6, tile = swz & 63;
    const int itile = tile >> 3, htile = tile & 7;
    f32x4 acc[4][2] = {};
    kloop2<true>(xt, BB, itile*128, ht, BB, htile*128, split*KCH, NT2, sm, acc);

    const int t = threadIdx.x, lane = t & 63, wid = t >> 6;
    const int wr = wid >> 2, wc = wid & 3;
    const int fr = lane & 15, kg = lane >> 4;
    const size_t pb = (size_t)split*II*HH;
    #pragma unroll
    for (int mf=0; mf<4; ++mf){
        const int i0 = itile*128 + wr*64 + mf*16 + kg*4;
        #pragma unroll
        for (int nf=0; nf<2; ++nf){
            const int h = htile*128 + wc*32 + nf*16 + fr;
            f16x4 pv = {(f16)acc[mf][nf][0],(f16)acc[mf][nf][1],
                        (f16)acc[mf][nf][2],(f16)acc[mf][nf][3]};
            *(f16x4*)&part[pb + (((size_t)(i0>>4)*(HH>>4) + (h>>4))<<8) + ((h&15)<<4) + (i0&15)] = pv;
        }
    }
}

__global__ __launch_bounds__(256) void k_final(const f16* __restrict__ part,
                                               const float* __restrict__ W,
                                               float* __restrict__ outW){
    const int T = (int)blockIdx.x*256 + threadIdx.x;   // 0..131071
    const int mt = T >> 5;                             // micro-tile (i>>4)*64+(h>>4)
    const int hl = (T & 31) >> 1;
    const int ihalf = T & 1;
    const int i0 = (mt >> 6)*16 + ihalf*8;
    const int h  = (mt & 63)*16 + hl;
    const size_t po = ((size_t)mt << 8) + (hl << 4) + ihalf*8;
    float s[8] = {};
    #pragma unroll
    for (int sp=0; sp<SPLIT; ++sp){
        f16x8 p = *(const f16x8*)&part[(size_t)sp*1048576 + po];
        #pragma unroll
        for (int e=0;e<8;++e) s[e] += (float)p[e];
    }
    const float SCALE = 3.0517578125e-07f;  // 0.01 / 32768
    #pragma unroll
    for (int e=0;e<8;++e){
        const size_t o = (size_t)(i0+e)*HH + h;
        outW[o] = fminf(1.f, fmaxf(-1.f, fmaf(SCALE, s[e], W[o])));
    }
}

extern "C" void kernel_launch(void* const* d_in, const int* in_sizes, int n_in,
                              void* d_out, int out_size, void* d_ws, size_t ws_size,
                              hipStream_t stream){
    (void)in_sizes; (void)n_in; (void)out_size; (void)ws_size;
    const float* x = (const float*)d_in[0];
    const float* W = (const float*)d_in[1];
    float* hidden = (float*)d_out;
    float* outW   = hidden + (size_t)BB*HH;
    char* ws = (char*)d_ws;
    // ws (194 MB, proven): xf f16 @0 (64MB) | xt f16 @64M | ht f16 (micro) @128M | wt f16 @192M
    //                      part f16 [8][I][H] (micro) @0 (16MB, overlaps dead xf)
    f16* xf   = (f16*)(ws);
    f16* xt   = (f16*)(ws + 67108864ull);
    f16* ht   = (f16*)(ws + 134217728ull);
    f16* wt   = (f16*)(ws + 201326592ull);
    f16* part = (f16*)(ws);

    k_prep<<<dim3(BB/64, II/64), 256, 0, stream>>>(x, xf, xt, II, BB);
    k_prep<<<dim3(II/64, HH/64), 256, 0, stream>>>(W, nullptr, wt, HH, II);
    k_gemm1<<<dim3((BB/128)*(HH/128)), 512, 0, stream>>>(xf, wt, hidden, ht);
    k_gemm2<<<dim3(64*SPLIT), 512, 0, stream>>>(xt, ht, part);
    k_final<<<dim3((II*HH)/(256*8)), 256, 0, stream>>>(part, W, outW);
}

// Round 10
// 211.988 us; speedup vs baseline: 1.2604x; 1.2604x over previous
//
#include <hip/hip_runtime.h>
#include <cstdint>

#define BB 32768
#define II 1024
#define HH 1024
#define SPLIT 16
#define KCH (BB/SPLIT)      // 2048
#define NT1 (II/64)         // 16 K-tiles (gemm1)
#define NT2 (KCH/64)        // 32 K-tiles per split (gemm2)

typedef _Float16 f16;
typedef _Float16 f16x4 __attribute__((ext_vector_type(4)));
typedef _Float16 f16x8 __attribute__((ext_vector_type(8)));
typedef float f32x4 __attribute__((ext_vector_type(4)));

typedef const __attribute__((address_space(1))) void gvoid_t;
typedef __attribute__((address_space(3))) void lvoid_t;

__device__ __forceinline__ void gload16(const void* g, void* l){
    __builtin_amdgcn_global_load_lds((gvoid_t*)g, (lvoid_t*)l, 16, 0, 0);
}

__device__ __forceinline__ float tanh_fast(float s){
    float a = fabsf(s);
    float e = __expf(-2.0f * a);
    float t = __fdividef(1.0f - e, 1.0f + e);
    return s < 0.0f ? -t : t;
}

// Fused prep: blocks [0,512): x [B][I] -> xf f16 + xt f16 [I][B]
//             blocks [512,528): W [I][H] -> wt f16 [H][I]
__global__ __launch_bounds__(256) void k_prep2(const float* __restrict__ x,
                                               f16* __restrict__ xf,
                                               f16* __restrict__ xt,
                                               const float* __restrict__ W,
                                               f16* __restrict__ wt){
    __shared__ float lt[64*67];
    const int t = threadIdx.x;
    const int bx = (int)blockIdx.x;
    const float* in; f16* cvt; f16* tr; int C, R, r0;
    if (bx < 512){ in = x; cvt = xf; tr = xt; C = II; R = BB; r0 = bx*64; }
    else         { in = W; cvt = nullptr; tr = wt; C = HH; R = II; r0 = (bx-512)*64; }
    const int c0 = blockIdx.y*64;
    #pragma unroll
    for (int p=0; p<4; ++p){
        int r = p*16 + (t>>4);
        int c = (t&15)*4;
        f32x4 v = __builtin_nontemporal_load((const f32x4*)&in[(size_t)(r0+r)*C + c0 + c]);
        if (cvt){
            f16x4 hv = {(f16)v[0],(f16)v[1],(f16)v[2],(f16)v[3]};
            *(f16x4*)&cvt[(size_t)(r0+r)*C + c0 + c] = hv;
        }
        lt[r*67 + c+0] = v[0];
        lt[r*67 + c+1] = v[1];
        lt[r*67 + c+2] = v[2];
        lt[r*67 + c+3] = v[3];
    }
    __syncthreads();
    const int c = t>>2, rb = (t&3)*16;
    f16x8 a, b;
    #pragma unroll
    for (int e=0; e<8; ++e) a[e] = (f16)lt[(rb+e)*67 + c];
    #pragma unroll
    for (int e=0; e<8; ++e) b[e] = (f16)lt[(rb+8+e)*67 + c];
    f16* o = &tr[(size_t)(c0+c)*R + r0 + rb];
    *(f16x8*)o = a;
    *(f16x8*)(o+8) = b;
}

// stage one 128x64-f16 half-tile (16KB) into linear LDS, source inverse-swizzled.
// LDS image byte b: row = b>>7, col c = (b&127) ^ (((b>>7)&7)<<4).
// MT=false: panel flat [row][ld] k-major. MT=true: 16x16 micro-tiled
// [h>>4][b>>4][h&15][b&15] f16.
template<bool MT>
__device__ __forceinline__ void stage_half(const f16* __restrict__ panel, int ld,
                                           int row0, int kcol0, char* lds_half,
                                           int wid, int lane){
    #pragma unroll
    for (int r=0;r<2;++r){
        int o = r*8192 + wid*1024 + lane*16;
        int rr = o>>7;
        int c0 = (o&127) ^ ((rr&7)<<4);
        if constexpr (!MT){
            const f16* src = panel + (size_t)(row0 + rr)*ld + kcol0 + (c0>>1);
            gload16(src, lds_half + r*8192 + wid*1024);
        } else {
            int h    = row0 + rr;
            int babs = kcol0 + (c0>>1);
            const f16* src = panel + (((size_t)(h>>4)*(BB>>4) + (babs>>4))<<8)
                                   + ((h&15)<<4) + (babs&8);
            gload16(src, lds_half + r*8192 + wid*1024);
        }
    }
}

#define RD_A(BUFA, mh) { \
    _Pragma("unroll") for (int m_=0;m_<4;++m_){ \
        af[m_][0] = *(const f16x8*)((BUFA) + rowA + (mh)*8192 + m_*2048 + ksw0); \
        af[m_][1] = *(const f16x8*)((BUFA) + rowA + (mh)*8192 + m_*2048 + ksw1); }}

#define RD_B(BUFB, nh) { \
    _Pragma("unroll") for (int n_=0;n_<2;++n_){ \
        bf[(nh)*2+n_][0] = *(const f16x8*)((BUFB) + rowB + (nh)*4096 + n_*2048 + ksw0); \
        bf[(nh)*2+n_][1] = *(const f16x8*)((BUFB) + rowB + (nh)*4096 + n_*2048 + ksw1); }}

#define MFMA_Q(mh,nh) { \
    __builtin_amdgcn_s_setprio(1); \
    _Pragma("unroll") for (int m_=0;m_<4;++m_){ \
      _Pragma("unroll") for (int n_=0;n_<2;++n_){ \
        _Pragma("unroll") for (int ks_=0;ks_<2;++ks_){ \
          acc[(mh)*4+m_][(nh)*2+n_] = __builtin_amdgcn_mfma_f32_16x16x32_f16( \
              af[m_][ks_], bf[(nh)*2+n_][ks_], acc[(mh)*4+m_][(nh)*2+n_], 0,0,0); }}} \
    __builtin_amdgcn_s_setprio(0); }

#define PH_SYNC1 { __builtin_amdgcn_s_barrier(); \
    asm volatile("s_waitcnt lgkmcnt(0)" ::: "memory"); \
    __builtin_amdgcn_sched_barrier(0); }
#define PH_SYNC2 { __builtin_amdgcn_s_barrier(); }
#define LGKM8 { asm volatile("s_waitcnt lgkmcnt(8)" ::: "memory"); }

// 256x256 tile, BK=64, 8 waves, 8-phase pipelined K-loop (T2+T3+T4+T5).
template<bool BMT>
__device__ __forceinline__ void kloop8(const f16* __restrict__ Ap, int lda, int arow0,
                                       const f16* __restrict__ Bp, int ldb, int brow0,
                                       int kbase, int nt, char* sm,
                                       f32x4 (&acc)[8][4])
{
    const int t = threadIdx.x, lane = t & 63, wid = t >> 6;
    const int wr = wid >> 2, wc = wid & 3;
    const int fr = lane & 15, kg = lane >> 4;
    const int mask = nt - 1;
    char* const A0 = sm;
    char* const B0 = sm + 32768;
    char* const A1 = sm + 65536;
    char* const B1 = sm + 98304;
    const int rowA = wr*16384 + fr*128;
    const int rowB = (wc>>1)*16384 + (wc&1)*8192 + fr*128;
    const int ksw0 = ((kg    ) ^ (fr & 7)) << 4;
    const int ksw1 = ((kg + 4) ^ (fr & 7)) << 4;

    f16x8 af[4][2], bf[4][2];

    // prologue: K0 -> buf0 (all 4 half-tiles), K1 -> B1 half0, A1 half0
    stage_half<false>(Ap, lda, arow0 +   0, kbase +  0, A0,         wid, lane);
    stage_half<false>(Ap, lda, arow0 + 128, kbase +  0, A0 + 16384, wid, lane);
    stage_half<BMT  >(Bp, ldb, brow0 +   0, kbase +  0, B0,         wid, lane);
    stage_half<BMT  >(Bp, ldb, brow0 + 128, kbase +  0, B0 + 16384, wid, lane);
    stage_half<BMT  >(Bp, ldb, brow0 +   0, kbase + 64, B1,         wid, lane);
    stage_half<false>(Ap, lda, arow0 +   0, kbase + 64, A1,         wid, lane);
    asm volatile("s_waitcnt vmcnt(4)" ::: "memory");
    __builtin_amdgcn_s_barrier();

    const int ni = nt >> 1;
    for (int it = 0; it < ni; ++it){
        const int k1 = (2*it + 1) * 64;
        const int k2 = ((2*it + 2) & mask) * 64;
        const int k3 = ((2*it + 3) & mask) * 64;
        // phase 1: Q(0,0) from buf0; stage A1 half1 (k1)
        RD_A(A0, 0); RD_B(B0, 0);
        stage_half<false>(Ap, lda, arow0 + 128, kbase + k1, A1 + 16384, wid, lane);
        LGKM8; PH_SYNC1; MFMA_Q(0,0); PH_SYNC2;
        // phase 2: Q(0,1); stage B1 half1 (k1)
        RD_B(B0, 1);
        stage_half<BMT>(Bp, ldb, brow0 + 128, kbase + k1, B1 + 16384, wid, lane);
        PH_SYNC1; MFMA_Q(0,1); PH_SYNC2;
        // phase 3: Q(1,0); stage B0 half0 (k2)
        RD_A(A0, 1);
        stage_half<BMT>(Bp, ldb, brow0 +   0, kbase + k2, B0, wid, lane);
        PH_SYNC1; MFMA_Q(1,0); PH_SYNC2;
        // phase 4: Q(1,1); stage A0 half0 (k2); counted vmcnt
        stage_half<false>(Ap, lda, arow0 +   0, kbase + k2, A0, wid, lane);
        PH_SYNC1; MFMA_Q(1,1);
        asm volatile("s_waitcnt vmcnt(4)" ::: "memory");
        __builtin_amdgcn_s_barrier();
        // phase 5: Q(0,0) from buf1; stage A0 half1 (k2)
        RD_A(A1, 0); RD_B(B1, 0);
        stage_half<false>(Ap, lda, arow0 + 128, kbase + k2, A0 + 16384, wid, lane);
        LGKM8; PH_SYNC1; MFMA_Q(0,0); PH_SYNC2;
        // phase 6: Q(0,1); stage B0 half1 (k2)
        RD_B(B1, 1);
        stage_half<BMT>(Bp, ldb, brow0 + 128, kbase + k2, B0 + 16384, wid, lane);
        PH_SYNC1; MFMA_Q(0,1); PH_SYNC2;
        // phase 7: Q(1,0); stage B1 half0 (k3)
        RD_A(A1, 1);
        stage_half<BMT>(Bp, ldb, brow0 +   0, kbase + k3, B1, wid, lane);
        PH_SYNC1; MFMA_Q(1,0); PH_SYNC2;
        // phase 8: Q(1,1); stage A1 half0 (k3); counted vmcnt
        stage_half<false>(Ap, lda, arow0 +   0, kbase + k3, A1, wid, lane);
        PH_SYNC1; MFMA_Q(1,1);
        asm volatile("s_waitcnt vmcnt(4)" ::: "memory");
        __builtin_amdgcn_s_barrier();
    }
    asm volatile("s_waitcnt vmcnt(0)" ::: "memory");
    __builtin_amdgcn_s_barrier();
}

// GEMM1: D[b][h] = sum_i xf[b][i]*wt[h][i]; hidden[b][h]=tanh (NT), ht=f16 micro-tiled.
__global__ __launch_bounds__(512,2) void k_gemm1(const f16* __restrict__ xf,
                                                 const f16* __restrict__ wt,
                                                 float* __restrict__ hidden,
                                                 f16* __restrict__ ht){
    __shared__ char sm[131072];
    const int bid = (int)blockIdx.x;
    const int swz = (bid & 7)*64 + (bid >> 3);
    const int btile = swz >> 2, htile = swz & 3;
    f32x4 acc[8][4] = {};
    kloop8<false>(xf, II, btile*256, wt, II, htile*256, 0, NT1, sm, acc);

    const int t = threadIdx.x, lane = t & 63, wid = t >> 6;
    const int wr = wid >> 2, wc = wid & 3;
    const int fr = lane & 15, kg = lane >> 4;
    const int b_base = btile*256 + wr*128 + kg*4;
    const int h_base = htile*256 + wc*64 + fr;
    #pragma unroll
    for (int mf=0; mf<8; ++mf){
        const int b = b_base + mf*16;
        #pragma unroll
        for (int nf=0; nf<4; ++nf){
            const int h = h_base + nf*16;
            float t0 = tanh_fast(acc[mf][nf][0]);
            float t1 = tanh_fast(acc[mf][nf][1]);
            float t2 = tanh_fast(acc[mf][nf][2]);
            float t3 = tanh_fast(acc[mf][nf][3]);
            f16x4 hv = {(f16)t0,(f16)t1,(f16)t2,(f16)t3};
            *(f16x4*)&ht[(((size_t)(h>>4)*(BB>>4) + (b>>4))<<8) + ((h&15)<<4) + (b&15)] = hv;
            // hidden: written once, never re-read on device -> non-temporal (keep L2/L3 for xt/ht)
            __builtin_nontemporal_store(t0, &hidden[(size_t)(b+0)*HH + h]);
            __builtin_nontemporal_store(t1, &hidden[(size_t)(b+1)*HH + h]);
            __builtin_nontemporal_store(t2, &hidden[(size_t)(b+2)*HH + h]);
            __builtin_nontemporal_store(t3, &hidden[(size_t)(b+3)*HH + h]);
        }
    }
}

// GEMM2: part[split] = xt-chunk @ ht-chunk^T, part micro-tiled [i>>4][h>>4][h&15][i&15].
__global__ __launch_bounds__(512,2) void k_gemm2(const f16* __restrict__ xt,
                                                 const f16* __restrict__ ht,
                                                 f16* __restrict__ part){
    __shared__ char sm[131072];
    const int bid = (int)blockIdx.x;
    const int swz = (bid & 7)*32 + (bid >> 3);
    const int split = swz >> 4, tile = swz & 15;
    const int itile = tile & 3, htile = tile >> 2;
    f32x4 acc[8][4] = {};
    kloop8<true>(xt, BB, itile*256, ht, BB, htile*256, split*KCH, NT2, sm, acc);

    const int t = threadIdx.x, lane = t & 63, wid = t >> 6;
    const int wr = wid >> 2, wc = wid & 3;
    const int fr = lane & 15, kg = lane >> 4;
    const size_t pb = (size_t)split*II*HH;
    #pragma unroll
    for (int mf=0; mf<8; ++mf){
        const int i0 = itile*256 + wr*128 + mf*16 + kg*4;
        #pragma unroll
        for (int nf=0; nf<4; ++nf){
            const int h = htile*256 + wc*64 + nf*16 + fr;
            f16x4 pv = {(f16)acc[mf][nf][0],(f16)acc[mf][nf][1],
                        (f16)acc[mf][nf][2],(f16)acc[mf][nf][3]};
            *(f16x4*)&part[pb + (((size_t)(i0>>4)*(HH>>4) + (h>>4))<<8) + ((h&15)<<4) + (i0&15)] = pv;
        }
    }
}

__global__ __launch_bounds__(256) void k_final(const f16* __restrict__ part,
                                               const float* __restrict__ W,
                                               float* __restrict__ outW){
    const int T = (int)blockIdx.x*256 + threadIdx.x;   // 0..131071
    const int mt = T >> 5;                             // micro-tile (i>>4)*64+(h>>4)
    const int hl = (T & 31) >> 1;
    const int ihalf = T & 1;
    const int i0 = (mt >> 6)*16 + ihalf*8;
    const int h  = (mt & 63)*16 + hl;
    const size_t po = ((size_t)mt << 8) + (hl << 4) + ihalf*8;
    float s[8] = {};
    #pragma unroll
    for (int sp=0; sp<SPLIT; ++sp){
        f16x8 p = __builtin_nontemporal_load((const f16x8*)&part[(size_t)sp*1048576 + po]);
        #pragma unroll
        for (int e=0;e<8;++e) s[e] += (float)p[e];
    }
    const float SCALE = 3.0517578125e-07f;  // 0.01 / 32768
    #pragma unroll
    for (int e=0;e<8;++e){
        const size_t o = (size_t)(i0+e)*HH + h;
        float r = fminf(1.f, fmaxf(-1.f, fmaf(SCALE, s[e], W[o])));
        __builtin_nontemporal_store(r, &outW[o]);
    }
}

extern "C" void kernel_launch(void* const* d_in, const int* in_sizes, int n_in,
                              void* d_out, int out_size, void* d_ws, size_t ws_size,
                              hipStream_t stream){
    (void)in_sizes; (void)n_in; (void)out_size; (void)ws_size;
    const float* x = (const float*)d_in[0];
    const float* W = (const float*)d_in[1];
    float* hidden = (float*)d_out;
    float* outW   = hidden + (size_t)BB*HH;
    char* ws = (char*)d_ws;
    // ws (194 MB, proven): xf f16 @0 (64MB) | xt f16 @64M | ht f16 (micro) @128M | wt f16 @192M
    //                      part f16 [16][I][H] (micro) @0 (32MB, overlaps dead xf)
    f16* xf   = (f16*)(ws);
    f16* xt   = (f16*)(ws + 67108864ull);
    f16* ht   = (f16*)(ws + 134217728ull);
    f16* wt   = (f16*)(ws + 201326592ull);
    f16* part = (f16*)(ws);

    k_prep2<<<dim3(528, 16), 256, 0, stream>>>(x, xf, xt, W, wt);
    k_gemm1<<<dim3((BB/256)*(HH/256)), 512, 0, stream>>>(xf, wt, hidden, ht);
    k_gemm2<<<dim3(16*SPLIT), 512, 0, stream>>>(xt, ht, part);
    k_final<<<dim3((II*HH)/(256*8)), 256, 0, stream>>>(part, W, outW);
}

// Round 11
// 207.038 us; speedup vs baseline: 1.2905x; 1.0239x over previous
//
#include <hip/hip_runtime.h>
#include <cstdint>

#define BB 32768
#define II 1024
#define HH 1024
#define SPLIT 16
#define KCH (BB/SPLIT)      // 2048
#define NT1 (II/64)         // 16 K-tiles (gemm1)
#define NT2 (KCH/64)        // 32 K-tiles per split (gemm2)

typedef _Float16 f16;
typedef _Float16 f16x4 __attribute__((ext_vector_type(4)));
typedef _Float16 f16x8 __attribute__((ext_vector_type(8)));
typedef float f32x4 __attribute__((ext_vector_type(4)));

typedef const __attribute__((address_space(1))) void gvoid_t;
typedef __attribute__((address_space(3))) void lvoid_t;

__device__ __forceinline__ void gload16(const void* g, void* l){
    __builtin_amdgcn_global_load_lds((gvoid_t*)g, (lvoid_t*)l, 16, 0, 0);
}

__device__ __forceinline__ float tanh_fast(float s){
    float a = fabsf(s);
    float e = __expf(-2.0f * a);
    float t = __fdividef(1.0f - e, 1.0f + e);
    return s < 0.0f ? -t : t;
}

// Fused prep: blocks [0,512): x [B][I] -> xf f16 + xt f16 [I][B]
//             blocks [512,528): W [I][H] -> wt f16 [H][I]
__global__ __launch_bounds__(256) void k_prep2(const float* __restrict__ x,
                                               f16* __restrict__ xf,
                                               f16* __restrict__ xt,
                                               const float* __restrict__ W,
                                               f16* __restrict__ wt){
    __shared__ float lt[64*67];
    const int t = threadIdx.x;
    const int bx = (int)blockIdx.x;
    const float* in; f16* cvt; f16* tr; int C, R, r0;
    if (bx < 512){ in = x; cvt = xf; tr = xt; C = II; R = BB; r0 = bx*64; }
    else         { in = W; cvt = nullptr; tr = wt; C = HH; R = II; r0 = (bx-512)*64; }
    const int c0 = blockIdx.y*64;
    #pragma unroll
    for (int p=0; p<4; ++p){
        int r = p*16 + (t>>4);
        int c = (t&15)*4;
        f32x4 v = __builtin_nontemporal_load((const f32x4*)&in[(size_t)(r0+r)*C + c0 + c]);
        if (cvt){
            f16x4 hv = {(f16)v[0],(f16)v[1],(f16)v[2],(f16)v[3]};
            *(f16x4*)&cvt[(size_t)(r0+r)*C + c0 + c] = hv;
        }
        lt[r*67 + c+0] = v[0];
        lt[r*67 + c+1] = v[1];
        lt[r*67 + c+2] = v[2];
        lt[r*67 + c+3] = v[3];
    }
    __syncthreads();
    const int c = t>>2, rb = (t&3)*16;
    f16x8 a, b;
    #pragma unroll
    for (int e=0; e<8; ++e) a[e] = (f16)lt[(rb+e)*67 + c];
    #pragma unroll
    for (int e=0; e<8; ++e) b[e] = (f16)lt[(rb+8+e)*67 + c];
    f16* o = &tr[(size_t)(c0+c)*R + r0 + rb];
    *(f16x8*)o = a;
    *(f16x8*)(o+8) = b;
}

// stage one 128x64-f16 half-tile (16KB) into linear LDS, source inverse-swizzled.
// LDS image byte b: row = b>>7, col c = (b&127) ^ (((b>>7)&7)<<4).
// MT=false: panel flat [row][ld] k-major. MT=true: 16x16 micro-tiled
// [h>>4][b>>4][h&15][b&15] f16.
template<bool MT>
__device__ __forceinline__ void stage_half(const f16* __restrict__ panel, int ld,
                                           int row0, int kcol0, char* lds_half,
                                           int wid, int lane){
    #pragma unroll
    for (int r=0;r<2;++r){
        int o = r*8192 + wid*1024 + lane*16;
        int rr = o>>7;
        int c0 = (o&127) ^ ((rr&7)<<4);
        if constexpr (!MT){
            const f16* src = panel + (size_t)(row0 + rr)*ld + kcol0 + (c0>>1);
            gload16(src, lds_half + r*8192 + wid*1024);
        } else {
            int h    = row0 + rr;
            int babs = kcol0 + (c0>>1);
            const f16* src = panel + (((size_t)(h>>4)*(BB>>4) + (babs>>4))<<8)
                                   + ((h&15)<<4) + (babs&8);
            gload16(src, lds_half + r*8192 + wid*1024);
        }
    }
}

#define RD_A(BUFA, mh) { \
    _Pragma("unroll") for (int m_=0;m_<4;++m_){ \
        af[m_][0] = *(const f16x8*)((BUFA) + rowA + (mh)*8192 + m_*2048 + ksw0); \
        af[m_][1] = *(const f16x8*)((BUFA) + rowA + (mh)*8192 + m_*2048 + ksw1); }}

#define RD_B(BUFB, nh) { \
    _Pragma("unroll") for (int n_=0;n_<2;++n_){ \
        bf[(nh)*2+n_][0] = *(const f16x8*)((BUFB) + rowB + (nh)*4096 + n_*2048 + ksw0); \
        bf[(nh)*2+n_][1] = *(const f16x8*)((BUFB) + rowB + (nh)*4096 + n_*2048 + ksw1); }}

#define MFMA_Q(mh,nh) { \
    __builtin_amdgcn_s_setprio(1); \
    _Pragma("unroll") for (int m_=0;m_<4;++m_){ \
      _Pragma("unroll") for (int n_=0;n_<2;++n_){ \
        _Pragma("unroll") for (int ks_=0;ks_<2;++ks_){ \
          acc[(mh)*4+m_][(nh)*2+n_] = __builtin_amdgcn_mfma_f32_16x16x32_f16( \
              af[m_][ks_], bf[(nh)*2+n_][ks_], acc[(mh)*4+m_][(nh)*2+n_], 0,0,0); }}} \
    __builtin_amdgcn_s_setprio(0); }

#define PH_SYNC1 { __builtin_amdgcn_s_barrier(); \
    asm volatile("s_waitcnt lgkmcnt(0)" ::: "memory"); \
    __builtin_amdgcn_sched_barrier(0); }
#define PH_SYNC2 { __builtin_amdgcn_s_barrier(); }
#define LGKM8 { asm volatile("s_waitcnt lgkmcnt(8)" ::: "memory"); }

// 256x256 tile, BK=64, 8 waves, 8-phase pipelined K-loop (T2+T3+T4+T5).
template<bool BMT>
__device__ __forceinline__ void kloop8(const f16* __restrict__ Ap, int lda, int arow0,
                                       const f16* __restrict__ Bp, int ldb, int brow0,
                                       int kbase, int nt, char* sm,
                                       f32x4 (&acc)[8][4])
{
    const int t = threadIdx.x, lane = t & 63, wid = t >> 6;
    const int wr = wid >> 2, wc = wid & 3;
    const int fr = lane & 15, kg = lane >> 4;
    const int mask = nt - 1;
    char* const A0 = sm;
    char* const B0 = sm + 32768;
    char* const A1 = sm + 65536;
    char* const B1 = sm + 98304;
    const int rowA = wr*16384 + fr*128;
    const int rowB = (wc>>1)*16384 + (wc&1)*8192 + fr*128;
    const int ksw0 = ((kg    ) ^ (fr & 7)) << 4;
    const int ksw1 = ((kg + 4) ^ (fr & 7)) << 4;

    f16x8 af[4][2], bf[4][2];

    // prologue: K0 -> buf0 (all 4 half-tiles), K1 -> B1 half0, A1 half0
    stage_half<false>(Ap, lda, arow0 +   0, kbase +  0, A0,         wid, lane);
    stage_half<false>(Ap, lda, arow0 + 128, kbase +  0, A0 + 16384, wid, lane);
    stage_half<BMT  >(Bp, ldb, brow0 +   0, kbase +  0, B0,         wid, lane);
    stage_half<BMT  >(Bp, ldb, brow0 + 128, kbase +  0, B0 + 16384, wid, lane);
    stage_half<BMT  >(Bp, ldb, brow0 +   0, kbase + 64, B1,         wid, lane);
    stage_half<false>(Ap, lda, arow0 +   0, kbase + 64, A1,         wid, lane);
    asm volatile("s_waitcnt vmcnt(4)" ::: "memory");
    __builtin_amdgcn_s_barrier();

    const int ni = nt >> 1;
    for (int it = 0; it < ni; ++it){
        const int k1 = (2*it + 1) * 64;
        const int k2 = ((2*it + 2) & mask) * 64;
        const int k3 = ((2*it + 3) & mask) * 64;
        // phase 1: Q(0,0) from buf0; stage A1 half1 (k1)
        RD_A(A0, 0); RD_B(B0, 0);
        stage_half<false>(Ap, lda, arow0 + 128, kbase + k1, A1 + 16384, wid, lane);
        LGKM8; PH_SYNC1; MFMA_Q(0,0); PH_SYNC2;
        // phase 2: Q(0,1); stage B1 half1 (k1)
        RD_B(B0, 1);
        stage_half<BMT>(Bp, ldb, brow0 + 128, kbase + k1, B1 + 16384, wid, lane);
        PH_SYNC1; MFMA_Q(0,1); PH_SYNC2;
        // phase 3: Q(1,0); stage B0 half0 (k2)
        RD_A(A0, 1);
        stage_half<BMT>(Bp, ldb, brow0 +   0, kbase + k2, B0, wid, lane);
        PH_SYNC1; MFMA_Q(1,0); PH_SYNC2;
        // phase 4: Q(1,1); stage A0 half0 (k2); counted vmcnt
        stage_half<false>(Ap, lda, arow0 +   0, kbase + k2, A0, wid, lane);
        PH_SYNC1; MFMA_Q(1,1);
        asm volatile("s_waitcnt vmcnt(4)" ::: "memory");
        __builtin_amdgcn_s_barrier();
        // phase 5: Q(0,0) from buf1; stage A0 half1 (k2)
        RD_A(A1, 0); RD_B(B1, 0);
        stage_half<false>(Ap, lda, arow0 + 128, kbase + k2, A0 + 16384, wid, lane);
        LGKM8; PH_SYNC1; MFMA_Q(0,0); PH_SYNC2;
        // phase 6: Q(0,1); stage B0 half1 (k2)
        RD_B(B1, 1);
        stage_half<BMT>(Bp, ldb, brow0 + 128, kbase + k2, B0 + 16384, wid, lane);
        PH_SYNC1; MFMA_Q(0,1); PH_SYNC2;
        // phase 7: Q(1,0); stage B1 half0 (k3)
        RD_A(A1, 1);
        stage_half<BMT>(Bp, ldb, brow0 +   0, kbase + k3, B1, wid, lane);
        PH_SYNC1; MFMA_Q(1,0); PH_SYNC2;
        // phase 8: Q(1,1); stage A1 half0 (k3); counted vmcnt
        stage_half<false>(Ap, lda, arow0 +   0, kbase + k3, A1, wid, lane);
        PH_SYNC1; MFMA_Q(1,1);
        asm volatile("s_waitcnt vmcnt(4)" ::: "memory");
        __builtin_amdgcn_s_barrier();
    }
    asm volatile("s_waitcnt vmcnt(0)" ::: "memory");
    __builtin_amdgcn_s_barrier();
}

// GEMM1: D[b][h] = sum_i xf[b][i]*wt[h][i]; hidden[b][h]=tanh, ht=f16 micro-tiled.
__global__ __launch_bounds__(512,2) void k_gemm1(const f16* __restrict__ xf,
                                                 const f16* __restrict__ wt,
                                                 float* __restrict__ hidden,
                                                 f16* __restrict__ ht){
    __shared__ char sm[131072];
    const int bid = (int)blockIdx.x;
    const int swz = (bid & 7)*64 + (bid >> 3);
    const int btile = swz >> 2, htile = swz & 3;
    f32x4 acc[8][4] = {};
    kloop8<false>(xf, II, btile*256, wt, II, htile*256, 0, NT1, sm, acc);

    const int t = threadIdx.x, lane = t & 63, wid = t >> 6;
    const int wr = wid >> 2, wc = wid & 3;
    const int fr = lane & 15, kg = lane >> 4;
    const int b_base = btile*256 + wr*128 + kg*4;
    const int h_base = htile*256 + wc*64 + fr;
    #pragma unroll
    for (int mf=0; mf<8; ++mf){
        const int b = b_base + mf*16;
        #pragma unroll
        for (int nf=0; nf<4; ++nf){
            const int h = h_base + nf*16;
            float t0 = tanh_fast(acc[mf][nf][0]);
            float t1 = tanh_fast(acc[mf][nf][1]);
            float t2 = tanh_fast(acc[mf][nf][2]);
            float t3 = tanh_fast(acc[mf][nf][3]);
            f16x4 hv = {(f16)t0,(f16)t1,(f16)t2,(f16)t3};
            *(f16x4*)&ht[(((size_t)(h>>4)*(BB>>4) + (b>>4))<<8) + ((h&15)<<4) + (b&15)] = hv;
            // plain stores: L2 write-combining merges the 64B segments (NT regressed, R10)
            hidden[(size_t)(b+0)*HH + h] = t0;
            hidden[(size_t)(b+1)*HH + h] = t1;
            hidden[(size_t)(b+2)*HH + h] = t2;
            hidden[(size_t)(b+3)*HH + h] = t3;
        }
    }
}

// GEMM2: part[split] = xt-chunk @ ht-chunk^T, part micro-tiled [i>>4][h>>4][h&15][i&15].
__global__ __launch_bounds__(512,2) void k_gemm2(const f16* __restrict__ xt,
                                                 const f16* __restrict__ ht,
                                                 f16* __restrict__ part){
    __shared__ char sm[131072];
    const int bid = (int)blockIdx.x;
    const int swz = (bid & 7)*32 + (bid >> 3);
    const int split = swz >> 4, tile = swz & 15;
    const int itile = tile & 3, htile = tile >> 2;
    f32x4 acc[8][4] = {};
    kloop8<true>(xt, BB, itile*256, ht, BB, htile*256, split*KCH, NT2, sm, acc);

    const int t = threadIdx.x, lane = t & 63, wid = t >> 6;
    const int wr = wid >> 2, wc = wid & 3;
    const int fr = lane & 15, kg = lane >> 4;
    const size_t pb = (size_t)split*II*HH;
    #pragma unroll
    for (int mf=0; mf<8; ++mf){
        const int i0 = itile*256 + wr*128 + mf*16 + kg*4;
        #pragma unroll
        for (int nf=0; nf<4; ++nf){
            const int h = htile*256 + wc*64 + nf*16 + fr;
            f16x4 pv = {(f16)acc[mf][nf][0],(f16)acc[mf][nf][1],
                        (f16)acc[mf][nf][2],(f16)acc[mf][nf][3]};
            *(f16x4*)&part[pb + (((size_t)(i0>>4)*(HH>>4) + (h>>4))<<8) + ((h&15)<<4) + (i0&15)] = pv;
        }
    }
}

__global__ __launch_bounds__(256) void k_final(const f16* __restrict__ part,
                                               const float* __restrict__ W,
                                               float* __restrict__ outW){
    const int T = (int)blockIdx.x*256 + threadIdx.x;   // 0..131071
    const int mt = T >> 5;                             // micro-tile (i>>4)*64+(h>>4)
    const int hl = (T & 31) >> 1;
    const int ihalf = T & 1;
    const int i0 = (mt >> 6)*16 + ihalf*8;
    const int h  = (mt & 63)*16 + hl;
    const size_t po = ((size_t)mt << 8) + (hl << 4) + ihalf*8;
    float s[8] = {};
    #pragma unroll
    for (int sp=0; sp<SPLIT; ++sp){
        f16x8 p = __builtin_nontemporal_load((const f16x8*)&part[(size_t)sp*1048576 + po]);
        #pragma unroll
        for (int e=0;e<8;++e) s[e] += (float)p[e];
    }
    const float SCALE = 3.0517578125e-07f;  // 0.01 / 32768
    #pragma unroll
    for (int e=0;e<8;++e){
        const size_t o = (size_t)(i0+e)*HH + h;
        float r = fminf(1.f, fmaxf(-1.f, fmaf(SCALE, s[e], W[o])));
        __builtin_nontemporal_store(r, &outW[o]);
    }
}

extern "C" void kernel_launch(void* const* d_in, const int* in_sizes, int n_in,
                              void* d_out, int out_size, void* d_ws, size_t ws_size,
                              hipStream_t stream){
    (void)in_sizes; (void)n_in; (void)out_size; (void)ws_size;
    const float* x = (const float*)d_in[0];
    const float* W = (const float*)d_in[1];
    float* hidden = (float*)d_out;
    float* outW   = hidden + (size_t)BB*HH;
    char* ws = (char*)d_ws;
    // ws (194 MB, proven): xf f16 @0 (64MB) | xt f16 @64M | ht f16 (micro) @128M | wt f16 @192M
    //                      part f16 [16][I][H] (micro) @0 (32MB, overlaps dead xf)
    f16* xf   = (f16*)(ws);
    f16* xt   = (f16*)(ws + 67108864ull);
    f16* ht   = (f16*)(ws + 134217728ull);
    f16* wt   = (f16*)(ws + 201326592ull);
    f16* part = (f16*)(ws);

    k_prep2<<<dim3(528, 16), 256, 0, stream>>>(x, xf, xt, W, wt);
    k_gemm1<<<dim3((BB/256)*(HH/256)), 512, 0, stream>>>(xf, wt, hidden, ht);
    k_gemm2<<<dim3(16*SPLIT), 512, 0, stream>>>(xt, ht, part);
    k_final<<<dim3((II*HH)/(256*8)), 256, 0, stream>>>(part, W, outW);
}